// Round 5
// baseline (66.348 us; speedup 1.0000x reference)
//
#include <hip/hip_runtime.h>

// Deimv2LQE: out = scores + MLP(top4-softmax-stats(pred_corners))
// 262144 rows; per row 132 f32 (4 corners x 33 bins).
// R5: same dataflow as R3 (best so far) but with ROLLED outer loops:
//     - substage loop (4x) rolled: one copy of the ~370-instr corner code
//     - MLP jc loop (4x) rolled: one copy of the ~370-instr MLP chunk
//     Code ~7 KB -> fits 32 KiB I$ (theory: R1-R4 were I$-fetch-bound:
//     VALUBusy pinned ~24% across all occupancy/LDS configs, cold==warm dur).
//     Inner loops stay unrolled so x[33]/st[20]/h[16] remain registers.
//     Barrier-free 1-wave blocks, reg-staged pipeline (load s+1 | compute s),
//     incremental stat writes, wave-uniform s_load MLP weights.

#define THREADS 64
#define ROWS 64
#define SUB 16   // rows per substage

__global__ __launch_bounds__(THREADS)
void lqe_kernel(const float* __restrict__ scores,
                const float* __restrict__ pc,
                const float* __restrict__ w1,
                const float* __restrict__ b1,
                const float* __restrict__ w2,
                const float* __restrict__ b2,
                float* __restrict__ out)
{
    __shared__ float sm_stage[SUB * 132];   // 8448 B, one 16-row substage
    __shared__ float sm_stat[ROWS * 21];    // 5376 B, stride 21 (odd)

    const int l = threadIdx.x;
    const long long rowBase = (long long)blockIdx.x * ROWS;

    const float myScore = scores[rowBase + l];

    const float4* __restrict__ src = (const float4*)(pc + rowBase * 132);
    float4* dst4 = (float4*)sm_stage;

    float4 ra[8], ta;

    // prologue: stage substage 0
    #pragma unroll
    for (int i = 0; i < 8; ++i) ra[i] = src[l + i * 64];
    if (l < 16) ta = src[512 + l];
    #pragma unroll
    for (int i = 0; i < 8; ++i) dst4[l + i * 64] = ra[i];
    if (l < 16) dst4[512 + l] = ta;

    float* const statp = sm_stat + (l >> 2) * 21 + (l & 3) * 5;

    #pragma unroll 1
    for (int s = 0; s < 4; ++s) {
        // issue next substage's global loads first (latency hides under compute)
        if (s < 3) {
            const float4* p = src + (s + 1) * 528;
            #pragma unroll
            for (int i = 0; i < 8; ++i) ra[i] = p[l + i * 64];
            if (l < 16) ta = p[512 + l];
        }

        // ---- corner task: row_local = l>>2, corner = l&3; LDS addr 33*l ----
        {
            const float* v = sm_stage + l * 33;
            float x[33];
            #pragma unroll
            for (int k = 0; k < 33; ++k) x[k] = v[k];

            // top-4 descending (t0..t3), branchless insertion network
            float t0 = x[0], t1 = x[1], t2 = x[2], t3 = x[3];
            float a;
            a = fmaxf(t0, t1); t1 = fminf(t0, t1); t0 = a;
            a = fmaxf(t2, t3); t3 = fminf(t2, t3); t2 = a;
            a = fmaxf(t0, t2); t2 = fminf(t0, t2); t0 = a;
            a = fmaxf(t1, t3); t3 = fminf(t1, t3); t1 = a;
            a = fmaxf(t1, t2); t2 = fminf(t1, t2); t1 = a;
            #pragma unroll
            for (int k = 4; k < 33; ++k) {
                float xx = x[k];
                a = fmaxf(t0, xx); xx = fminf(t0, xx); t0 = a;
                a = fmaxf(t1, xx); xx = fminf(t1, xx); t1 = a;
                a = fmaxf(t2, xx); xx = fminf(t2, xx); t2 = a;
                t3 = fmaxf(t3, xx);
            }

            float ssum = 0.f;
            #pragma unroll
            for (int k = 0; k < 33; ++k) ssum += __expf(x[k] - t0);
            const float inv = 1.0f / ssum;
            const float p0 = inv;
            const float p1 = __expf(t1 - t0) * inv;
            const float p2 = __expf(t2 - t0) * inv;
            const float p3 = __expf(t3 - t0) * inv;
            const float pm = 0.25f * (p0 + p1 + p2 + p3);

            float* sd = statp + s * (SUB * 21);
            sd[0] = p0; sd[1] = p1; sd[2] = p2; sd[3] = p3; sd[4] = pm;
        }

        // write next substage into LDS (after this substage's reads; DS ops
        // are in-order within a wave -> WAR-safe, no barrier)
        if (s < 3) {
            #pragma unroll
            for (int i = 0; i < 8; ++i) dst4[l + i * 64] = ra[i];
            if (l < 16) dst4[512 + l] = ta;
        }
    }

    // ---- MLP: lane-per-row; weight indices wave-uniform -> s_load ----
    float st[20];
    #pragma unroll
    for (int k = 0; k < 20; ++k) st[k] = sm_stat[l * 21 + k];

    float acc = 0.f;
    #pragma unroll 1
    for (int jc = 0; jc < 4; ++jc) {
        const float* __restrict__ w1c = w1 + jc * 16;
        const float* __restrict__ w2c = w2 + jc * 16;
        const float* __restrict__ b1c = b1 + jc * 16;
        float h[16];
        #pragma unroll
        for (int j = 0; j < 16; ++j) h[j] = b1c[j];
        #pragma unroll
        for (int k = 0; k < 20; ++k) {
            #pragma unroll
            for (int j = 0; j < 16; ++j)
                h[j] = fmaf(st[k], w1c[k * 64 + j], h[j]);
        }
        #pragma unroll
        for (int j = 0; j < 16; ++j)
            acc = fmaf(fmaxf(h[j], 0.f), w2c[j], acc);
    }

    out[rowBase + l] = myScore + acc + b2[0];
}

extern "C" void kernel_launch(void* const* d_in, const int* in_sizes, int n_in,
                              void* d_out, int out_size, void* d_ws, size_t ws_size,
                              hipStream_t stream) {
    const float* scores = (const float*)d_in[0];
    const float* pc     = (const float*)d_in[1];
    const float* w1     = (const float*)d_in[2];
    const float* b1     = (const float*)d_in[3];
    const float* w2     = (const float*)d_in[4];
    const float* b2     = (const float*)d_in[5];
    float* out = (float*)d_out;

    const int rows = out_size;          // 262144
    const int blocks = rows / ROWS;     // 4096
    lqe_kernel<<<blocks, THREADS, 0, stream>>>(scores, pc, w1, b1, w2, b2, out);
}

// Round 6
// 41.343 us; speedup vs baseline: 1.6048x; 1.6048x over previous
//
#include <hip/hip_runtime.h>

// Deimv2LQE: out = scores + MLP(top4-softmax-stats(pred_corners))
// 262144 rows; per row 132 f32 (4 corners x 33 bins).
// R6: NO LDS staging. Each lane loads its corner's 33 floats directly from
//     global (8x dwordx4 + 1 dword, dword-aligned; a wave still touches one
//     contiguous 8448B span per substage -> same cache-line traffic as the
//     staged version, minus ~70 DS ops/lane and the LDS WAR serialization).
//     Block = 256 threads = 4 fully independent waves (no __syncthreads),
//     each wave owns 64 rows + a private 5376B stat slice (stride 21, odd).
//     __launch_bounds__(256,4) caps VGPR at 128 -> 16 waves/CU available.
//     MLP lane-per-row, wave-uniform weight indices -> s_load path.

#define THREADS 256

typedef float f32x4 __attribute__((ext_vector_type(4), aligned(4)));

__global__ __launch_bounds__(THREADS, 4)
void lqe_kernel(const float* __restrict__ scores,
                const float* __restrict__ pc,
                const float* __restrict__ w1,
                const float* __restrict__ b1,
                const float* __restrict__ w2,
                const float* __restrict__ b2,
                float* __restrict__ out)
{
    __shared__ float sm_stat[4][64 * 21];   // 21504 B total, per-wave slices

    const int tid = threadIdx.x;
    const int wv = tid >> 6;
    const int l  = tid & 63;
    float* const statS = sm_stat[wv];

    const long long waveRowBase = (long long)blockIdx.x * 256 + wv * 64;

    const float myScore = scores[waveRowBase + l];

    // ---- corner phase: 4 substages x (16 rows x 4 corners = 64 tasks) ----
    #pragma unroll
    for (int s = 0; s < 4; ++s) {
        const float* base =
            pc + (waveRowBase + s * 16 + (l >> 2)) * 132 + (l & 3) * 33;

        float x[33];
        #pragma unroll
        for (int i = 0; i < 8; ++i) {
            f32x4 v = *(const f32x4*)(base + i * 4);
            x[i * 4 + 0] = v.x; x[i * 4 + 1] = v.y;
            x[i * 4 + 2] = v.z; x[i * 4 + 3] = v.w;
        }
        x[32] = base[32];

        // top-4 descending (t0..t3), branchless insertion network
        float t0 = x[0], t1 = x[1], t2 = x[2], t3 = x[3];
        float a;
        a = fmaxf(t0, t1); t1 = fminf(t0, t1); t0 = a;
        a = fmaxf(t2, t3); t3 = fminf(t2, t3); t2 = a;
        a = fmaxf(t0, t2); t2 = fminf(t0, t2); t0 = a;
        a = fmaxf(t1, t3); t3 = fminf(t1, t3); t1 = a;
        a = fmaxf(t1, t2); t2 = fminf(t1, t2); t1 = a;
        #pragma unroll
        for (int k = 4; k < 33; ++k) {
            float xx = x[k];
            a = fmaxf(t0, xx); xx = fminf(t0, xx); t0 = a;
            a = fmaxf(t1, xx); xx = fminf(t1, xx); t1 = a;
            a = fmaxf(t2, xx); xx = fminf(t2, xx); t2 = a;
            t3 = fmaxf(t3, xx);
        }

        float ssum = 0.f;
        #pragma unroll
        for (int k = 0; k < 33; ++k) ssum += __expf(x[k] - t0);
        const float inv = 1.0f / ssum;
        const float p0 = inv;
        const float p1 = __expf(t1 - t0) * inv;
        const float p2 = __expf(t2 - t0) * inv;
        const float p3 = __expf(t3 - t0) * inv;
        const float pm = 0.25f * (p0 + p1 + p2 + p3);

        float* sd = statS + (s * 16 + (l >> 2)) * 21 + (l & 3) * 5;
        sd[0] = p0; sd[1] = p1; sd[2] = p2; sd[3] = p3; sd[4] = pm;
    }

    // ---- MLP: lane-per-row within the wave's private slice ----
    // (DS ops are dependency-ordered within a wave; no barrier needed.)
    float st[20];
    #pragma unroll
    for (int k = 0; k < 20; ++k) st[k] = statS[l * 21 + k];

    float acc = 0.f;
    #pragma unroll
    for (int jc = 0; jc < 4; ++jc) {
        float h[16];
        #pragma unroll
        for (int j = 0; j < 16; ++j) h[j] = b1[jc * 16 + j];
        #pragma unroll
        for (int k = 0; k < 20; ++k) {
            #pragma unroll
            for (int j = 0; j < 16; ++j)
                h[j] = fmaf(st[k], w1[k * 64 + jc * 16 + j], h[j]);
        }
        #pragma unroll
        for (int j = 0; j < 16; ++j)
            acc = fmaf(fmaxf(h[j], 0.f), w2[jc * 16 + j], acc);
    }

    out[waveRowBase + l] = myScore + acc + b2[0];
}

extern "C" void kernel_launch(void* const* d_in, const int* in_sizes, int n_in,
                              void* d_out, int out_size, void* d_ws, size_t ws_size,
                              hipStream_t stream) {
    const float* scores = (const float*)d_in[0];
    const float* pc     = (const float*)d_in[1];
    const float* w1     = (const float*)d_in[2];
    const float* b1     = (const float*)d_in[3];
    const float* w2     = (const float*)d_in[4];
    const float* b2     = (const float*)d_in[5];
    float* out = (float*)d_out;

    const int rows = out_size;            // 262144
    const int blocks = rows / 256;        // 1024
    lqe_kernel<<<blocks, THREADS, 0, stream>>>(scores, pc, w1, b1, w2, b2, out);
}